// Round 3
// baseline (469.972 us; speedup 1.0000x reference)
//
#include <hip/hip_runtime.h>
#include <hip/hip_bf16.h>
#include <math.h>

#define B_ 32
#define N_ 128
#define L_ 1024
#define DD_ 256
#define TD_ 1280
#define HID_ 512
#define H_ 8
#define HD_ 64

// ws layout (float offsets)
#define WS_D    0
#define WS_RM   (WS_D   + 2097152)
#define WS_RIZ  (WS_RM  + 32768)
#define WS_RMT  (WS_RIZ + 32768)
#define WS_RZT  (WS_RMT + 524288)
#define WS_RWT  (WS_RZT + 524288)
#define WS_CNT  (WS_RWT + 524288)
#define WS_WT   (WS_CNT + 64)
#define WS_THB  (WS_WT  + 327680)
#define WS_DWB  (WS_THB + 8388608)

using bf16x8 = __attribute__((ext_vector_type(8))) short;
using floatx4 = __attribute__((ext_vector_type(4))) float;

static __device__ __forceinline__ unsigned short f2bf(float f) {
  unsigned int u = __float_as_uint(f);
  unsigned int r = (u + 0x7FFFu + ((u >> 16) & 1u)) >> 16;
  return (unsigned short)r;
}
static __device__ __forceinline__ float bf2f(unsigned short s) {
  return __uint_as_float(((unsigned int)s) << 16);
}
// async global->LDS DMA, 16 B per lane; LDS dest = wave-uniform base + lane*16.
static __device__ __forceinline__ void gload16(const void* g, void* l) {
  __builtin_amdgcn_global_load_lds(
      (const __attribute__((address_space(1))) void*)g,
      (__attribute__((address_space(3))) void*)l, 16, 0, 0);
}

// ---------------------------------------------------------------------------
// K0: per-batch valid counts (detect int32 vs packed-bool at runtime).
// ---------------------------------------------------------------------------
__global__ __launch_bounds__(256) void count_kernel(const int* __restrict__ dmask,
                                                    const int* __restrict__ tmask,
                                                    int* __restrict__ cnts) {
  __shared__ int red[256];
  const int b = blockIdx.x, tid = threadIdx.x;
  const bool dint = (dmask[0] == 1);
  const bool tint = (tmask[0] == 1);
  int s = 0;
  if (dint) {
    for (int i = tid; i < N_; i += 256) s += (dmask[(size_t)b*N_ + i] != 0);
  } else {
    const unsigned char* p = (const unsigned char*)dmask;
    for (int i = tid; i < N_; i += 256) s += (p[(size_t)b*N_ + i] != 0);
  }
  red[tid] = s; __syncthreads();
  for (int off = 128; off > 0; off >>= 1) { if (tid < off) red[tid] += red[tid+off]; __syncthreads(); }
  if (tid == 0) cnts[b*2] = red[0];
  __syncthreads();
  s = 0;
  if (tint) {
    for (int i = tid; i < L_; i += 256) s += (tmask[(size_t)b*L_ + i] != 0);
  } else {
    const unsigned char* p = (const unsigned char*)tmask;
    for (int i = tid; i < L_; i += 256) s += (p[(size_t)b*L_ + i] != 0);
  }
  red[tid] = s; __syncthreads();
  for (int off = 128; off > 0; off >>= 1) { if (tid < off) red[tid] += red[tid+off]; __syncthreads(); }
  if (tid == 0) cnts[b*2+1] = red[0];
}

// ---------------------------------------------------------------------------
// K0b: W (KxN fp32) -> WT (NxK bf16), 32x32 LDS tiles.
// ---------------------------------------------------------------------------
__global__ __launch_bounds__(256) void transpose_bf16_kernel(
    const float* __restrict__ W, unsigned short* __restrict__ WT, int K, int Nd) {
  __shared__ float tile[32][33];
  const int tid = threadIdx.x;
  const int n0 = blockIdx.x * 32, k0 = blockIdx.y * 32;
  const int c = tid & 31, r0 = tid >> 5;
#pragma unroll
  for (int i = 0; i < 4; i++) {
    const int r = r0 + i * 8;
    tile[c][r] = W[(size_t)(k0 + r) * Nd + n0 + c];
  }
  __syncthreads();
#pragma unroll
  for (int i = 0; i < 4; i++) {
    const int r = r0 + i * 8;
    WT[(size_t)(n0 + r) * K + k0 + c] = f2bf(tile[r][c]);
  }
}

// ---------------------------------------------------------------------------
// K1: t-projection, fused fp32->bf16, FULL double-buffer (As[2], Bs[2],
// 64 KB LDS -> 2 blocks/CU) with a SINGLE barrier per K-step (T3 minimum):
//   iter t: aload(t+1); bstage(nxt, t+1)   // both prefetches issued first
//           compute(As[cur], Bs[cur])      // MFMA phase covers the latencies
//           awrite(As[nxt])                // waits apf only (vmcnt FIFO: the 8
//                                          //   B-DMAs issued after stay in flight)
//           __syncthreads()                // lone drain; B-DMA had ~full phase
// Writes target the opposite buffer, so no pre-write barrier is needed.
// m99/m100 measured this dbuf config at 839-890 TF on 128^2 tiles.
// XOR quad-swizzle on As/Bs slots keeps ds_read/ds_write <=2-way (free).
// ---------------------------------------------------------------------------
__global__ __launch_bounds__(256) void gemm_t_mfma_kernel(
    const float* __restrict__ A, const unsigned short* __restrict__ WT,
    const float* __restrict__ bias, unsigned short* __restrict__ thb, int K) {
  __shared__ __align__(16) unsigned short As[2][8192];  // 2 kgroups x 512 slots x 8
  __shared__ __align__(16) unsigned short Bs[2][8192];
  const int tid = threadIdx.x;
  const int lin = blockIdx.x;
  const int xcd = lin & 7, sq = lin >> 3;
  const int n_t = sq & 3, m_t = (sq >> 2) + xcd * 32;
  const int m0 = m_t * 128, n0 = n_t * 128;
  const int lane = tid & 63, wave = tid >> 6;
  const int wm = wave & 1, wn = wave >> 1;
  const int quad = lane >> 4, lrow = lane & 15;

  floatx4 acc[4][4];
#pragma unroll
  for (int i = 0; i < 4; i++)
#pragma unroll
    for (int j = 0; j < 4; j++) acc[i][j] = (floatx4){0.f, 0.f, 0.f, 0.f};

  // B staging source offsets (two calls x two kgroups)
  int srcoff[2][2];   // [call][g] element offset within row-block
#pragma unroll
  for (int call = 0; call < 2; call++) {
    const int i = call * 256 + tid;
    const int r = i >> 2;
    const int c = (i & 3) ^ ((r >> 1) & 3);
#pragma unroll
    for (int g = 0; g < 2; g++) srcoff[call][g] = r * K + g * 32 + c * 8;
  }

  // A staging map: thread covers rows {ar_, ar_+64}, 16 consecutive k each.
  const int ar_ = tid >> 2;            // 0..63
  const int kc_ = (tid & 3) * 16;      // k offset within the 64-k tile
  const int g_  = kc_ >> 5;            // kgroup 0/1
  const int cq0 = (kc_ & 31) >> 3;     // first global 8-k chunk (0 or 2)

  const float* Abase = A + (size_t)m0 * K;
  const unsigned short* Bbase = WT + (size_t)n0 * K;

  float4 apf[2][4];

  auto aload = [&](int k0) {
#pragma unroll
    for (int i = 0; i < 2; i++) {
      const float* src = Abase + (size_t)(ar_ + i * 64) * K + k0 + kc_;
#pragma unroll
      for (int j = 0; j < 4; j++) apf[i][j] = *(const float4*)(src + j * 4);
    }
  };
  auto awrite = [&](int buf) {
#pragma unroll
    for (int i = 0; i < 2; i++) {
      const int r = ar_ + i * 64;
      const int sw = (r >> 1) & 3;
      union { unsigned short s[16]; bf16x8 v[2]; } p;
#pragma unroll
      for (int j = 0; j < 4; j++) {
        p.s[j * 4 + 0] = f2bf(apf[i][j].x);
        p.s[j * 4 + 1] = f2bf(apf[i][j].y);
        p.s[j * 4 + 2] = f2bf(apf[i][j].z);
        p.s[j * 4 + 3] = f2bf(apf[i][j].w);
      }
      *(bf16x8*)&As[buf][g_ * 4096 + (r * 4 + ((cq0 + 0) ^ sw)) * 8] = p.v[0];
      *(bf16x8*)&As[buf][g_ * 4096 + (r * 4 + ((cq0 + 1) ^ sw)) * 8] = p.v[1];
    }
  };
  auto bstage = [&](int buf, int k0) {
#pragma unroll
    for (int g = 0; g < 2; g++)
#pragma unroll
      for (int call = 0; call < 2; call++) {
        const int dst = g * 4096 + (call * 256 + wave * 64) * 8;
        gload16(Bbase + k0 + srcoff[call][g], &Bs[buf][dst]);
      }
  };

  const int nkt = K / 64;   // 20

  // prologue: stage tile 0 into buffer 0
  aload(0);
  bstage(0, 0);
  awrite(0);                // compiler waits vmcnt for apf; B-DMA stays issued
  __syncthreads();          // drains B-DMA(0); As[0]/Bs[0] visible

  int cur = 0;
  for (int t = 0; t < nkt; t++) {
    const int nxt = cur ^ 1;
    if (t + 1 < nkt) {
      aload((t + 1) * 64);          // A fp32 loads in flight across compute
      bstage(nxt, (t + 1) * 64);    // B DMA in flight across compute
    }
#pragma unroll
    for (int g = 0; g < 2; g++) {
      bf16x8 bfr[4];
#pragma unroll
      for (int j = 0; j < 4; j++) {
        const int br = wn * 64 + j * 16 + lrow;
        bfr[j] = *(const bf16x8*)&Bs[cur][g * 4096 + (br * 4 + (quad ^ ((br >> 1) & 3))) * 8];
      }
#pragma unroll
      for (int i = 0; i < 4; i++) {
        const int ar = wm * 64 + i * 16 + lrow;
        bf16x8 afr = *(const bf16x8*)&As[cur][g * 4096 + (ar * 4 + (quad ^ ((ar >> 1) & 3))) * 8];
#pragma unroll
        for (int j = 0; j < 4; j++)
          acc[i][j] = __builtin_amdgcn_mfma_f32_16x16x32_bf16(afr, bfr[j], acc[i][j], 0, 0, 0);
      }
    }
    if (t + 1 < nkt) awrite(nxt);   // waits apf only; writes opposite buffer
    __syncthreads();                // lone drain per K-step
    cur = nxt;
  }

  float bj[4];
#pragma unroll
  for (int j = 0; j < 4; j++) bj[j] = bias[n0 + wn * 64 + j * 16 + lrow];
#pragma unroll
  for (int i = 0; i < 4; i++) {
#pragma unroll
    for (int j = 0; j < 4; j++) {
      const int gcol = n0 + wn * 64 + j * 16 + lrow;
      const int hh = gcol >> 6, e = gcol & 63;
#pragma unroll
      for (int r = 0; r < 4; r++) {
        const int grow = m0 + wm * 64 + i * 16 + quad * 4 + r;
        const int bb = grow >> 10, l = grow & 1023;
        thb[(((size_t)bb * H_ + hh) * L_ + l) * HD_ + e] = f2bf(acc[i][j][r] + bj[j]);
      }
    }
  }
}

// ---------------------------------------------------------------------------
// K2: fp32 GEMM for the small d-projection (keeps dproj exact for ctx_t).
// ---------------------------------------------------------------------------
__global__ __launch_bounds__(256) void gemm_bias_kernel(
    const float* __restrict__ A, const float* __restrict__ W,
    const float* __restrict__ bias, float* __restrict__ C,
    int M, int K, int Nd) {
  __shared__ float As[8][132];
  __shared__ float Bs[8][132];
  const int tid = threadIdx.x;
  const int m0 = blockIdx.y * 128, n0 = blockIdx.x * 128;
  const int lr = tid >> 1, lc = (tid & 1) * 4;
  const int wr = tid >> 5, wc = (tid & 31) * 4;
  const int tm = (tid >> 4) * 4, tn = (tid & 15) * 4;

  float acc[2][2][4][4];
#pragma unroll
  for (int a = 0; a < 2; a++)
#pragma unroll
    for (int bq = 0; bq < 2; bq++)
#pragma unroll
      for (int i = 0; i < 4; i++)
#pragma unroll
        for (int j = 0; j < 4; j++) acc[a][bq][i][j] = 0.f;

  const float* Aptr = A + (size_t)(m0 + lr) * K + lc;
  const float* Wptr = W + (size_t)wr * Nd + n0 + wc;

  for (int k0 = 0; k0 < K; k0 += 8) {
    float4 a4 = *(const float4*)(Aptr + k0);
    float4 w4 = *(const float4*)(Wptr + (size_t)k0 * Nd);
    __syncthreads();
    As[lc+0][lr] = a4.x; As[lc+1][lr] = a4.y; As[lc+2][lr] = a4.z; As[lc+3][lr] = a4.w;
    *(float4*)&Bs[wr][wc] = w4;
    __syncthreads();
#pragma unroll
    for (int kk = 0; kk < 8; kk++) {
      float4 a0 = *(const float4*)&As[kk][tm];
      float4 a1 = *(const float4*)&As[kk][tm + 64];
      float4 b0 = *(const float4*)&Bs[kk][tn];
      float4 b1 = *(const float4*)&Bs[kk][tn + 64];
      const float av0[4] = {a0.x, a0.y, a0.z, a0.w};
      const float av1[4] = {a1.x, a1.y, a1.z, a1.w};
      const float bv0[4] = {b0.x, b0.y, b0.z, b0.w};
      const float bv1[4] = {b1.x, b1.y, b1.z, b1.w};
#pragma unroll
      for (int i = 0; i < 4; i++)
#pragma unroll
        for (int j = 0; j < 4; j++) {
          acc[0][0][i][j] += av0[i] * bv0[j];
          acc[0][1][i][j] += av0[i] * bv1[j];
          acc[1][0][i][j] += av1[i] * bv0[j];
          acc[1][1][i][j] += av1[i] * bv1[j];
        }
    }
  }
  float4 bias0 = *(const float4*)&bias[n0 + tn];
  float4 bias1 = *(const float4*)&bias[n0 + tn + 64];
  const float bb0[4] = {bias0.x, bias0.y, bias0.z, bias0.w};
  const float bb1[4] = {bias1.x, bias1.y, bias1.z, bias1.w};
#pragma unroll
  for (int mh = 0; mh < 2; mh++)
#pragma unroll
    for (int i = 0; i < 4; i++) {
      const int row = m0 + mh * 64 + tm + i;
      float* cp = C + (size_t)row * Nd + n0;
      float4 o0, o1;
      o0.x = acc[mh][0][i][0] + bb0[0]; o0.y = acc[mh][0][i][1] + bb0[1];
      o0.z = acc[mh][0][i][2] + bb0[2]; o0.w = acc[mh][0][i][3] + bb0[3];
      o1.x = acc[mh][1][i][0] + bb1[0]; o1.y = acc[mh][1][i][1] + bb1[1];
      o1.z = acc[mh][1][i][2] + bb1[2]; o1.w = acc[mh][1][i][3] + bb1[3];
      *(float4*)(cp + tn) = o0;
      *(float4*)(cp + tn + 64) = o1;
    }
}

// ---------------------------------------------------------------------------
// K3: dWb[b][h][n][e] = (dh @ Wb[h]) in bf16. grid = 256 (hb = b*8+h).
// ---------------------------------------------------------------------------
__global__ __launch_bounds__(256) void dw_kernel(
    const float* __restrict__ dproj, const float* __restrict__ Wb,
    unsigned short* __restrict__ dWb) {
  __shared__ float wb_s[64 * 64];
  const int tid = threadIdx.x;
  const int hb = blockIdx.x, b = hb >> 3, h = hb & 7;
  for (int i = tid; i < 4096; i += 256) wb_s[i] = Wb[(size_t)h * 4096 + i];
  __syncthreads();
  const int n = tid >> 1, half = tid & 1;
  float acc[32];
#pragma unroll
  for (int e = 0; e < 32; e++) acc[e] = 0.f;
  const float* dpr = dproj + ((size_t)(b * N_ + n)) * HID_ + h * HD_;
  for (int k = 0; k < 64; k++) {
    const float a = dpr[k];
    const float* wr = &wb_s[k * 64 + half * 32];
#pragma unroll
    for (int e = 0; e < 32; e++) acc[e] += a * wr[e];
  }
  unsigned short* outp = dWb + ((size_t)hb * N_ + n) * HD_ + half * 32;
#pragma unroll
  for (int e = 0; e < 32; e++) outp[e] = f2bf(acc[e]);
}

// ---------------------------------------------------------------------------
// S-tile (128n x 64l) via MFMA, operands from global bf16 head-major arrays;
// masked fp32 S to LDS (stride 69: conflict-light on row and column walks).
// ---------------------------------------------------------------------------
__device__ __forceinline__ void mfma_S_tile(
    const unsigned short* __restrict__ thp, const unsigned short* __restrict__ dwp,
    float* __restrict__ S_s, int ncnt, int lv, int tid) {
  const int lane = tid & 63, wave = tid >> 6;
  const int quad = lane >> 4, lr = lane & 15;
  const int noff = (wave & 1) * 64, loff = (wave >> 1) * 32;

  floatx4 acc[4][2];
#pragma unroll
  for (int i = 0; i < 4; i++)
#pragma unroll
    for (int j = 0; j < 2; j++) acc[i][j] = (floatx4){0.f, 0.f, 0.f, 0.f};

#pragma unroll
  for (int kc = 0; kc < 2; kc++) {
    bf16x8 bfr[2];
#pragma unroll
    for (int j = 0; j < 2; j++)
      bfr[j] = *(const bf16x8*)&thp[(size_t)(loff + j * 16 + lr) * HD_ + kc * 32 + quad * 8];
#pragma unroll
    for (int i = 0; i < 4; i++) {
      bf16x8 afr = *(const bf16x8*)&dwp[(size_t)(noff + i * 16 + lr) * HD_ + kc * 32 + quad * 8];
#pragma unroll
      for (int j = 0; j < 2; j++)
        acc[i][j] = __builtin_amdgcn_mfma_f32_16x16x32_bf16(afr, bfr[j], acc[i][j], 0, 0, 0);
    }
  }
#pragma unroll
  for (int i = 0; i < 4; i++)
#pragma unroll
    for (int j = 0; j < 2; j++)
#pragma unroll
      for (int r = 0; r < 4; r++) {
        const int n = noff + i * 16 + quad * 4 + r;
        const int li = loff + j * 16 + lr;
        const bool ok = (n < ncnt) && (li < lv);
        S_s[n * 69 + li] = ok ? acc[i][j][r] : -1e9f;
      }
}

// ---------------------------------------------------------------------------
// K4: per (hb, lt): S tile -> column softmax (complete per tile); per-tile
// row stats (m_t, z_t) and per-tile w partial (no atomics). grid = 256*16.
// ---------------------------------------------------------------------------
__global__ __launch_bounds__(256, 4) void attn_stats_kernel(
    const unsigned short* __restrict__ thb, const unsigned short* __restrict__ dWb,
    const int* __restrict__ cnts, float* __restrict__ rwt,
    float* __restrict__ rmt, float* __restrict__ rzt) {
  __shared__ float S_s[128 * 69];
  __shared__ float red[256];
  __shared__ float zb_s[256], wb_s[256];
  __shared__ float cm_s[64], ics_s[64];
  const int tid = threadIdx.x;
  const int hb = blockIdx.x >> 4, lt = blockIdx.x & 15;
  const int b = hb >> 3;
  const int ncnt = cnts[b * 2], lcnt = cnts[b * 2 + 1];
  const int l0g = lt * 64;
  if (l0g >= lcnt) return;
  const int lv = min(64, lcnt - l0g);

  mfma_S_tile(thb + ((size_t)hb * L_ + l0g) * HD_, dWb + (size_t)hb * N_ * HD_,
              S_s, ncnt, lv, tid);
  __syncthreads();

  {  // column max partials (over n)
    const int l = tid & 63, q = tid >> 6;
    float pm = -INFINITY;
    for (int n = q * 32; n < q * 32 + 32; n++) pm = fmaxf(pm, S_s[n * 69 + l]);
    red[tid] = pm;
  }
  __syncthreads();
  if (tid < 64)
    cm_s[tid] = fmaxf(fmaxf(red[tid], red[tid + 64]), fmaxf(red[tid + 128], red[tid + 192]));
  __syncthreads();
  {  // column expsum partials
    const int l = tid & 63, q = tid >> 6;
    const float cm = cm_s[l];
    float ps = 0.f;
    for (int n = q * 32; n < q * 32 + 32; n++) ps += __expf(S_s[n * 69 + l] - cm);
    red[tid] = ps;
  }
  __syncthreads();
  if (tid < 64)
    ics_s[tid] = 1.f / (red[tid] + red[tid + 64] + red[tid + 128] + red[tid + 192]);
  __syncthreads();
  {  // row pass, split across halves: n = tid&127, half covers 32 l's
    const int n = tid & 127, half = tid >> 7;
    const float* Sr = &S_s[n * 69];
    const int lb = half * 32, le = min(lb + 32, lv);
    float tmax = -INFINITY;
    for (int l = lb; l < le; l++) tmax = fmaxf(tmax, Sr[l]);
    red[tid] = tmax;
    __syncthreads();
    const float tm = fmaxf(red[n], red[n + 128]);
    float z = 0.f, w = 0.f;
    for (int l = lb; l < le; l++) {
      const float s = Sr[l];
      z += __expf(s - tm);
      w += __expf(s - cm_s[l]) * ics_s[l];
    }
    zb_s[tid] = z; wb_s[tid] = w;
    __syncthreads();
    if (tid < 128) {
      const size_t o = ((size_t)hb * 16 + lt) * 128 + tid;
      rmt[o] = tm;
      rzt[o] = zb_s[tid] + zb_s[tid + 128];
      rwt[o] = wb_s[tid] + wb_s[tid + 128];
    }
  }
}

// ---------------------------------------------------------------------------
// K5: combine per-tile row stats -> (m, 1/Z) and w; finalize ctx_t. grid=256.
// ---------------------------------------------------------------------------
__global__ __launch_bounds__(256) void attn_combine_kernel(
    const float* __restrict__ rmt, const float* __restrict__ rzt,
    const float* __restrict__ rwt, const float* __restrict__ dproj,
    const int* __restrict__ cnts, float* __restrict__ rm_g,
    float* __restrict__ riz_g, float* __restrict__ outp) {
  __shared__ float red[256];
  __shared__ float w_s[128];
  const int tid = threadIdx.x;
  const int hb = blockIdx.x, b = hb >> 3, h = hb & 7;
  const int ncnt = cnts[b * 2], lcnt = cnts[b * 2 + 1];
  const int ntl = (lcnt + 63) >> 6;
  if (tid < 128) {
    const int n = tid;
    float m = -INFINITY;
    for (int t = 0; t < ntl; t++)
      m = fmaxf(m, rmt[((size_t)hb * 16 + t) * 128 + n]);
    float Z = 0.f, w = 0.f;
    for (int t = 0; t < ntl; t++) {
      const size_t o = ((size_t)hb * 16 + t) * 128 + n;
      Z += rzt[o] * __expf(rmt[o] - m);
      w += rwt[o];
    }
    rm_g[hb * 128 + n] = m;
    riz_g[hb * 128 + n] = (n < ncnt) ? 1.f / Z : 0.f;
    w_s[n] = (n < ncnt) ? w : 0.f;
  }
  __syncthreads();
  const int e = tid & 63, q = tid >> 6;
  float p = 0.f;
  const int nb = q * 32, ne = min(nb + 32, ncnt);
  for (int n = nb; n < ne; n++)
    p += w_s[n] * dproj[((size_t)(b * N_ + n)) * HID_ + h * HD_ + e];
  red[tid] = p;
  __syncthreads();
  if (tid < 64) {
    const float s = red[tid] + red[tid + 64] + red[tid + 128] + red[tid + 192];
    outp[(size_t)b * (2 * HID_) + HID_ + h * HD_ + tid] = s / (float)lcnt;
  }
}

// ---------------------------------------------------------------------------
// K6: recompute S tile; v[l] = sum_n exp(S-m[n])/Z[n]; fused ctx_d partial
// accumulation (atomicAdd into zero-initialized out). grid = 256*16.
// ---------------------------------------------------------------------------
__global__ __launch_bounds__(256, 4) void attn_v_kernel(
    const unsigned short* __restrict__ thb, const unsigned short* __restrict__ dWb,
    const int* __restrict__ cnts, const float* __restrict__ rm_g,
    const float* __restrict__ riz_g, float* __restrict__ outp) {
  __shared__ float S_s[128 * 69];
  __shared__ float red[256];
  __shared__ float rm_s[128], riz_s[128], v_s[64];
  const int tid = threadIdx.x;
  const int hb = blockIdx.x >> 4, lt = blockIdx.x & 15;
  const int b = hb >> 3, h = hb & 7;
  const int ncnt = cnts[b * 2], lcnt = cnts[b * 2 + 1];
  const int l0g = lt * 64;
  if (l0g >= lcnt) return;
  const int lv = min(64, lcnt - l0g);

  if (tid < 128) {
    rm_s[tid] = rm_g[hb * 128 + tid];
    riz_s[tid] = riz_g[hb * 128 + tid];
  }
  const unsigned short* thp = thb + ((size_t)hb * L_ + l0g) * HD_;
  mfma_S_tile(thp, dWb + (size_t)hb * N_ * HD_, S_s, ncnt, lv, tid);
  __syncthreads();

  {
    const int l = tid & 63, q = tid >> 6;
    float vp = 0.f;
    for (int n = q * 32; n < q * 32 + 32; n++)
      vp += __expf(S_s[n * 69 + l] - rm_s[n]) * riz_s[n];
    red[tid] = vp;
  }
  __syncthreads();
  const float incnt = 1.f / (float)ncnt;
  if (tid < 64) {
    const float v = (tid < lv)
        ? (red[tid] + red[tid + 64] + red[tid + 128] + red[tid + 192]) * incnt
        : 0.f;
    v_s[tid] = v;
  }
  __syncthreads();
  {  // fused ctx_d partial: sum_{l in tile} v[l] * th[l][e]
    const int e = tid & 63, q = tid >> 6;
    float p = 0.f;
    for (int l = q * 16; l < q * 16 + 16; l++)
      p += v_s[l] * bf2f(thp[(size_t)l * HD_ + e]);
    red[tid] = p;
  }
  __syncthreads();
  if (tid < 64) {
    const float s = red[tid] + red[tid + 64] + red[tid + 128] + red[tid + 192];
    if (s != 0.f)
      atomicAdd(&outp[(size_t)b * (2 * HID_) + h * HD_ + tid], s);
  }
}

// ---------------------------------------------------------------------------
extern "C" void kernel_launch(void* const* d_in, const int* in_sizes, int n_in,
                              void* d_out, int out_size, void* d_ws, size_t ws_size,
                              hipStream_t stream) {
  const float* drug = (const float*)d_in[0];
  const int* dmask = (const int*)d_in[1];
  const float* tseq = (const float*)d_in[2];
  const int* tmask = (const int*)d_in[3];
  const float* Wd = (const float*)d_in[4];
  const float* bd = (const float*)d_in[5];
  const float* Wt = (const float*)d_in[6];
  const float* bt = (const float*)d_in[7];
  const float* Wb = (const float*)d_in[8];
  float* out = (float*)d_out;
  float* ws = (float*)d_ws;

  float* dp = ws + WS_D;
  float* rm = ws + WS_RM;
  float* riz = ws + WS_RIZ;
  float* rmt = ws + WS_RMT;
  float* rzt = ws + WS_RZT;
  float* rwt = ws + WS_RWT;
  int* cnts = (int*)(ws + WS_CNT);
  unsigned short* wtT = (unsigned short*)(ws + WS_WT);
  unsigned short* thb = (unsigned short*)(ws + WS_THB);
  unsigned short* dWb = (unsigned short*)(ws + WS_DWB);

  count_kernel<<<B_, 256, 0, stream>>>(dmask, tmask, cnts);
  hipMemsetAsync(out, 0, (size_t)out_size * sizeof(float), stream);
  transpose_bf16_kernel<<<dim3(HID_ / 32, TD_ / 32), 256, 0, stream>>>(Wt, wtT, TD_, HID_);
  gemm_t_mfma_kernel<<<(HID_ / 128) * ((B_ * L_) / 128), 256, 0, stream>>>(
      tseq, wtT, bt, thb, TD_);
  gemm_bias_kernel<<<dim3(HID_ / 128, (B_ * N_) / 128), 256, 0, stream>>>(
      drug, Wd, bd, dp, B_ * N_, DD_, HID_);
  dw_kernel<<<B_ * H_, 256, 0, stream>>>(dp, Wb, dWb);
  attn_stats_kernel<<<B_ * H_ * 16, 256, 0, stream>>>(thb, dWb, cnts, rwt, rmt, rzt);
  attn_combine_kernel<<<B_ * H_, 256, 0, stream>>>(rmt, rzt, rwt, dp, cnts, rm, riz, out);
  attn_v_kernel<<<B_ * H_ * 16, 256, 0, stream>>>(thb, dWb, cnts, rm, riz, out);
}

// Round 4
// 454.868 us; speedup vs baseline: 1.0332x; 1.0332x over previous
//
#include <hip/hip_runtime.h>
#include <hip/hip_bf16.h>
#include <math.h>

#define B_ 32
#define N_ 128
#define L_ 1024
#define DD_ 256
#define TD_ 1280
#define HID_ 512
#define H_ 8
#define HD_ 64

// ws layout (float offsets)
#define WS_D    0
#define WS_RM   (WS_D   + 2097152)
#define WS_RIZ  (WS_RM  + 32768)
#define WS_RMT  (WS_RIZ + 32768)
#define WS_RZT  (WS_RMT + 524288)
#define WS_RWT  (WS_RZT + 524288)
#define WS_CNT  (WS_RWT + 524288)
#define WS_WT   (WS_CNT + 64)
#define WS_THB  (WS_WT  + 327680)
#define WS_DWB  (WS_THB + 8388608)

using bf16x8 = __attribute__((ext_vector_type(8))) short;
using u16x4 = __attribute__((ext_vector_type(4))) unsigned short;
using floatx4 = __attribute__((ext_vector_type(4))) float;

static __device__ __forceinline__ unsigned short f2bf(float f) {
  unsigned int u = __float_as_uint(f);
  unsigned int r = (u + 0x7FFFu + ((u >> 16) & 1u)) >> 16;
  return (unsigned short)r;
}
static __device__ __forceinline__ float bf2f(unsigned short s) {
  return __uint_as_float(((unsigned int)s) << 16);
}
// async global->LDS DMA, 16 B per lane; LDS dest = wave-uniform base + lane*16.
static __device__ __forceinline__ void gload16(const void* g, void* l) {
  __builtin_amdgcn_global_load_lds(
      (const __attribute__((address_space(1))) void*)g,
      (__attribute__((address_space(3))) void*)l, 16, 0, 0);
}

// ---------------------------------------------------------------------------
// K0: per-batch valid counts (detect int32 vs packed-bool at runtime).
// ---------------------------------------------------------------------------
__global__ __launch_bounds__(256) void count_kernel(const int* __restrict__ dmask,
                                                    const int* __restrict__ tmask,
                                                    int* __restrict__ cnts) {
  __shared__ int red[256];
  const int b = blockIdx.x, tid = threadIdx.x;
  const bool dint = (dmask[0] == 1);
  const bool tint = (tmask[0] == 1);
  int s = 0;
  if (dint) {
    for (int i = tid; i < N_; i += 256) s += (dmask[(size_t)b*N_ + i] != 0);
  } else {
    const unsigned char* p = (const unsigned char*)dmask;
    for (int i = tid; i < N_; i += 256) s += (p[(size_t)b*N_ + i] != 0);
  }
  red[tid] = s; __syncthreads();
  for (int off = 128; off > 0; off >>= 1) { if (tid < off) red[tid] += red[tid+off]; __syncthreads(); }
  if (tid == 0) cnts[b*2] = red[0];
  __syncthreads();
  s = 0;
  if (tint) {
    for (int i = tid; i < L_; i += 256) s += (tmask[(size_t)b*L_ + i] != 0);
  } else {
    const unsigned char* p = (const unsigned char*)tmask;
    for (int i = tid; i < L_; i += 256) s += (p[(size_t)b*L_ + i] != 0);
  }
  red[tid] = s; __syncthreads();
  for (int off = 128; off > 0; off >>= 1) { if (tid < off) red[tid] += red[tid+off]; __syncthreads(); }
  if (tid == 0) cnts[b*2+1] = red[0];
}

// ---------------------------------------------------------------------------
// K0b: W (KxN fp32) -> WT (NxK bf16), 32x32 LDS tiles.
// ---------------------------------------------------------------------------
__global__ __launch_bounds__(256) void transpose_bf16_kernel(
    const float* __restrict__ W, unsigned short* __restrict__ WT, int K, int Nd) {
  __shared__ float tile[32][33];
  const int tid = threadIdx.x;
  const int n0 = blockIdx.x * 32, k0 = blockIdx.y * 32;
  const int c = tid & 31, r0 = tid >> 5;
#pragma unroll
  for (int i = 0; i < 4; i++) {
    const int r = r0 + i * 8;
    tile[c][r] = W[(size_t)(k0 + r) * Nd + n0 + c];
  }
  __syncthreads();
#pragma unroll
  for (int i = 0; i < 4; i++) {
    const int r = r0 + i * 8;
    WT[(size_t)(n0 + r) * K + k0 + c] = f2bf(tile[r][c]);
  }
}

// ---------------------------------------------------------------------------
// K1: t-projection, fused fp32->bf16. Round-2 structure (32 KB LDS, 4
// blocks/CU, 2 barriers/K-step) with a COALESCED A-load map: instruction i,
// lane l reads row i*16 + wave*4 + (l>>4), cols (l&15)*4..+3 -> 16 lanes
// cover one row's full 256-B k-slice, 4 rows/instr = 16 fully-consumed
// 64-B lines, zero line re-touch (old map touched 64 scattered 16-B pieces
// per instr and re-touched each line 4x across j -> request-rate bound).
// Each thread then cvt's 4 floats -> 4 bf16 -> one ds_write_b64 into the
// XOR-swizzled slot layout (read side unchanged).
// ---------------------------------------------------------------------------
__global__ __launch_bounds__(256) void gemm_t_mfma_kernel(
    const float* __restrict__ A, const unsigned short* __restrict__ WT,
    const float* __restrict__ bias, unsigned short* __restrict__ thb, int K) {
  __shared__ __align__(16) unsigned short As[8192];   // 2 kgroups x 512 slots x 8
  __shared__ __align__(16) unsigned short Bs[8192];
  const int tid = threadIdx.x;
  const int lin = blockIdx.x;
  const int xcd = lin & 7, sq = lin >> 3;
  const int n_t = sq & 3, m_t = (sq >> 2) + xcd * 32;
  const int m0 = m_t * 128, n0 = n_t * 128;
  const int lane = tid & 63, wave = tid >> 6;
  const int wm = wave & 1, wn = wave >> 1;
  const int quad = lane >> 4, lrow = lane & 15;

  floatx4 acc[4][4];
#pragma unroll
  for (int i = 0; i < 4; i++)
#pragma unroll
    for (int j = 0; j < 4; j++) acc[i][j] = (floatx4){0.f, 0.f, 0.f, 0.f};

  // B staging source offsets (two calls x two kgroups)
  int srcoff[2][2];   // [call][g] element offset within row-block
#pragma unroll
  for (int call = 0; call < 2; call++) {
    const int i = call * 256 + tid;
    const int r = i >> 2;
    const int c = (i & 3) ^ ((r >> 1) & 3);
#pragma unroll
    for (int g = 0; g < 2; g++) srcoff[call][g] = r * K + g * 32 + c * 8;
  }

  // A staging map (coalesced): instr i covers rows i*16 + arow_ (4 rows/wave),
  // lane's 16-lane group spans one row's 64 contiguous floats.
  const int arow_ = wave * 4 + (lane >> 4);   // base row 0..15
  const int x_ = lane & 15;                    // 16-B column slot (x_*4 floats)
  const int ag_ = x_ >> 3;                     // kgroup 0/1
  const int acq_ = (x_ & 7) >> 1;              // 8-col chunk within group
  const int ahalf_ = x_ & 1;                   // half-slot (4 shorts)

  const float* Abase = A + (size_t)m0 * K;
  const unsigned short* Bbase = WT + (size_t)n0 * K;

  float4 apf[8];

  auto aload = [&](int k0) {
#pragma unroll
    for (int i = 0; i < 8; i++)
      apf[i] = *(const float4*)(Abase + (size_t)(i * 16 + arow_) * K + k0 + x_ * 4);
  };
  auto awrite = [&]() {
#pragma unroll
    for (int i = 0; i < 8; i++) {
      const int r = i * 16 + arow_;
      const int sw = (r >> 1) & 3;
      u16x4 p;
      p[0] = f2bf(apf[i].x); p[1] = f2bf(apf[i].y);
      p[2] = f2bf(apf[i].z); p[3] = f2bf(apf[i].w);
      *(u16x4*)&As[ag_ * 4096 + (r * 4 + (acq_ ^ sw)) * 8 + ahalf_ * 4] = p;
    }
  };
  auto bstage = [&](int k0) {
#pragma unroll
    for (int g = 0; g < 2; g++)
#pragma unroll
      for (int call = 0; call < 2; call++) {
        const int dst = g * 4096 + (call * 256 + wave * 64) * 8;
        gload16(Bbase + k0 + srcoff[call][g], &Bs[dst]);
      }
  };

  const int nkt = K / 64;   // 20
  aload(0);

  for (int t = 0; t < nkt; t++) {
    __syncthreads();        // all waves done with As/Bs(t-1); drains apf loads
    bstage(t * 64);         // B DMA issue
    awrite();               // As <- cvt(apf); apf older than DMA in vmcnt FIFO
    __syncthreads();        // drains B DMA; As/Bs(t) visible
    if (t + 1 < nkt) aload((t + 1) * 64);   // in flight across MFMA phase
#pragma unroll
    for (int g = 0; g < 2; g++) {
      bf16x8 bfr[4];
#pragma unroll
      for (int j = 0; j < 4; j++) {
        const int br = wn * 64 + j * 16 + lrow;
        bfr[j] = *(const bf16x8*)&Bs[g * 4096 + (br * 4 + (quad ^ ((br >> 1) & 3))) * 8];
      }
#pragma unroll
      for (int i = 0; i < 4; i++) {
        const int ar = wm * 64 + i * 16 + lrow;
        bf16x8 afr = *(const bf16x8*)&As[g * 4096 + (ar * 4 + (quad ^ ((ar >> 1) & 3))) * 8];
#pragma unroll
        for (int j = 0; j < 4; j++)
          acc[i][j] = __builtin_amdgcn_mfma_f32_16x16x32_bf16(afr, bfr[j], acc[i][j], 0, 0, 0);
      }
    }
  }

  float bj[4];
#pragma unroll
  for (int j = 0; j < 4; j++) bj[j] = bias[n0 + wn * 64 + j * 16 + lrow];
#pragma unroll
  for (int i = 0; i < 4; i++) {
#pragma unroll
    for (int j = 0; j < 4; j++) {
      const int gcol = n0 + wn * 64 + j * 16 + lrow;
      const int hh = gcol >> 6, e = gcol & 63;
#pragma unroll
      for (int r = 0; r < 4; r++) {
        const int grow = m0 + wm * 64 + i * 16 + quad * 4 + r;
        const int bb = grow >> 10, l = grow & 1023;
        thb[(((size_t)bb * H_ + hh) * L_ + l) * HD_ + e] = f2bf(acc[i][j][r] + bj[j]);
      }
    }
  }
}

// ---------------------------------------------------------------------------
// K2: fp32 GEMM for the small d-projection (keeps dproj exact for ctx_t).
// ---------------------------------------------------------------------------
__global__ __launch_bounds__(256) void gemm_bias_kernel(
    const float* __restrict__ A, const float* __restrict__ W,
    const float* __restrict__ bias, float* __restrict__ C,
    int M, int K, int Nd) {
  __shared__ float As[8][132];
  __shared__ float Bs[8][132];
  const int tid = threadIdx.x;
  const int m0 = blockIdx.y * 128, n0 = blockIdx.x * 128;
  const int lr = tid >> 1, lc = (tid & 1) * 4;
  const int wr = tid >> 5, wc = (tid & 31) * 4;
  const int tm = (tid >> 4) * 4, tn = (tid & 15) * 4;

  float acc[2][2][4][4];
#pragma unroll
  for (int a = 0; a < 2; a++)
#pragma unroll
    for (int bq = 0; bq < 2; bq++)
#pragma unroll
      for (int i = 0; i < 4; i++)
#pragma unroll
        for (int j = 0; j < 4; j++) acc[a][bq][i][j] = 0.f;

  const float* Aptr = A + (size_t)(m0 + lr) * K + lc;
  const float* Wptr = W + (size_t)wr * Nd + n0 + wc;

  for (int k0 = 0; k0 < K; k0 += 8) {
    float4 a4 = *(const float4*)(Aptr + k0);
    float4 w4 = *(const float4*)(Wptr + (size_t)k0 * Nd);
    __syncthreads();
    As[lc+0][lr] = a4.x; As[lc+1][lr] = a4.y; As[lc+2][lr] = a4.z; As[lc+3][lr] = a4.w;
    *(float4*)&Bs[wr][wc] = w4;
    __syncthreads();
#pragma unroll
    for (int kk = 0; kk < 8; kk++) {
      float4 a0 = *(const float4*)&As[kk][tm];
      float4 a1 = *(const float4*)&As[kk][tm + 64];
      float4 b0 = *(const float4*)&Bs[kk][tn];
      float4 b1 = *(const float4*)&Bs[kk][tn + 64];
      const float av0[4] = {a0.x, a0.y, a0.z, a0.w};
      const float av1[4] = {a1.x, a1.y, a1.z, a1.w};
      const float bv0[4] = {b0.x, b0.y, b0.z, b0.w};
      const float bv1[4] = {b1.x, b1.y, b1.z, b1.w};
#pragma unroll
      for (int i = 0; i < 4; i++)
#pragma unroll
        for (int j = 0; j < 4; j++) {
          acc[0][0][i][j] += av0[i] * bv0[j];
          acc[0][1][i][j] += av0[i] * bv1[j];
          acc[1][0][i][j] += av1[i] * bv0[j];
          acc[1][1][i][j] += av1[i] * bv1[j];
        }
    }
  }
  float4 bias0 = *(const float4*)&bias[n0 + tn];
  float4 bias1 = *(const float4*)&bias[n0 + tn + 64];
  const float bb0[4] = {bias0.x, bias0.y, bias0.z, bias0.w};
  const float bb1[4] = {bias1.x, bias1.y, bias1.z, bias1.w};
#pragma unroll
  for (int mh = 0; mh < 2; mh++)
#pragma unroll
    for (int i = 0; i < 4; i++) {
      const int row = m0 + mh * 64 + tm + i;
      float* cp = C + (size_t)row * Nd + n0;
      float4 o0, o1;
      o0.x = acc[mh][0][i][0] + bb0[0]; o0.y = acc[mh][0][i][1] + bb0[1];
      o0.z = acc[mh][0][i][2] + bb0[2]; o0.w = acc[mh][0][i][3] + bb0[3];
      o1.x = acc[mh][1][i][0] + bb1[0]; o1.y = acc[mh][1][i][1] + bb1[1];
      o1.z = acc[mh][1][i][2] + bb1[2]; o1.w = acc[mh][1][i][3] + bb1[3];
      *(float4*)(cp + tn) = o0;
      *(float4*)(cp + tn + 64) = o1;
    }
}

// ---------------------------------------------------------------------------
// K3: dWb[b][h][n][e] = (dh @ Wb[h]) in bf16. grid = 256 (hb = b*8+h).
// ---------------------------------------------------------------------------
__global__ __launch_bounds__(256) void dw_kernel(
    const float* __restrict__ dproj, const float* __restrict__ Wb,
    unsigned short* __restrict__ dWb) {
  __shared__ float wb_s[64 * 64];
  const int tid = threadIdx.x;
  const int hb = blockIdx.x, b = hb >> 3, h = hb & 7;
  for (int i = tid; i < 4096; i += 256) wb_s[i] = Wb[(size_t)h * 4096 + i];
  __syncthreads();
  const int n = tid >> 1, half = tid & 1;
  float acc[32];
#pragma unroll
  for (int e = 0; e < 32; e++) acc[e] = 0.f;
  const float* dpr = dproj + ((size_t)(b * N_ + n)) * HID_ + h * HD_;
  for (int k = 0; k < 64; k++) {
    const float a = dpr[k];
    const float* wr = &wb_s[k * 64 + half * 32];
#pragma unroll
    for (int e = 0; e < 32; e++) acc[e] += a * wr[e];
  }
  unsigned short* outp = dWb + ((size_t)hb * N_ + n) * HD_ + half * 32;
#pragma unroll
  for (int e = 0; e < 32; e++) outp[e] = f2bf(acc[e]);
}

// ---------------------------------------------------------------------------
// S-tile (128n x 64l) via MFMA, operands from global bf16 head-major arrays;
// masked fp32 S to LDS (stride 69: conflict-light on row and column walks).
// ---------------------------------------------------------------------------
__device__ __forceinline__ void mfma_S_tile(
    const unsigned short* __restrict__ thp, const unsigned short* __restrict__ dwp,
    float* __restrict__ S_s, int ncnt, int lv, int tid) {
  const int lane = tid & 63, wave = tid >> 6;
  const int quad = lane >> 4, lr = lane & 15;
  const int noff = (wave & 1) * 64, loff = (wave >> 1) * 32;

  floatx4 acc[4][2];
#pragma unroll
  for (int i = 0; i < 4; i++)
#pragma unroll
    for (int j = 0; j < 2; j++) acc[i][j] = (floatx4){0.f, 0.f, 0.f, 0.f};

#pragma unroll
  for (int kc = 0; kc < 2; kc++) {
    bf16x8 bfr[2];
#pragma unroll
    for (int j = 0; j < 2; j++)
      bfr[j] = *(const bf16x8*)&thp[(size_t)(loff + j * 16 + lr) * HD_ + kc * 32 + quad * 8];
#pragma unroll
    for (int i = 0; i < 4; i++) {
      bf16x8 afr = *(const bf16x8*)&dwp[(size_t)(noff + i * 16 + lr) * HD_ + kc * 32 + quad * 8];
#pragma unroll
      for (int j = 0; j < 2; j++)
        acc[i][j] = __builtin_amdgcn_mfma_f32_16x16x32_bf16(afr, bfr[j], acc[i][j], 0, 0, 0);
    }
  }
#pragma unroll
  for (int i = 0; i < 4; i++)
#pragma unroll
    for (int j = 0; j < 2; j++)
#pragma unroll
      for (int r = 0; r < 4; r++) {
        const int n = noff + i * 16 + quad * 4 + r;
        const int li = loff + j * 16 + lr;
        const bool ok = (n < ncnt) && (li < lv);
        S_s[n * 69 + li] = ok ? acc[i][j][r] : -1e9f;
      }
}

// ---------------------------------------------------------------------------
// K4: per (hb, lt): S tile -> column softmax (complete per tile); per-tile
// row stats (m_t, z_t) and per-tile w partial (no atomics). grid = 256*16.
// ---------------------------------------------------------------------------
__global__ __launch_bounds__(256, 4) void attn_stats_kernel(
    const unsigned short* __restrict__ thb, const unsigned short* __restrict__ dWb,
    const int* __restrict__ cnts, float* __restrict__ rwt,
    float* __restrict__ rmt, float* __restrict__ rzt) {
  __shared__ float S_s[128 * 69];
  __shared__ float red[256];
  __shared__ float zb_s[256], wb_s[256];
  __shared__ float cm_s[64], ics_s[64];
  const int tid = threadIdx.x;
  const int hb = blockIdx.x >> 4, lt = blockIdx.x & 15;
  const int b = hb >> 3;
  const int ncnt = cnts[b * 2], lcnt = cnts[b * 2 + 1];
  const int l0g = lt * 64;
  if (l0g >= lcnt) return;
  const int lv = min(64, lcnt - l0g);

  mfma_S_tile(thb + ((size_t)hb * L_ + l0g) * HD_, dWb + (size_t)hb * N_ * HD_,
              S_s, ncnt, lv, tid);
  __syncthreads();

  {  // column max partials (over n)
    const int l = tid & 63, q = tid >> 6;
    float pm = -INFINITY;
    for (int n = q * 32; n < q * 32 + 32; n++) pm = fmaxf(pm, S_s[n * 69 + l]);
    red[tid] = pm;
  }
  __syncthreads();
  if (tid < 64)
    cm_s[tid] = fmaxf(fmaxf(red[tid], red[tid + 64]), fmaxf(red[tid + 128], red[tid + 192]));
  __syncthreads();
  {  // column expsum partials
    const int l = tid & 63, q = tid >> 6;
    const float cm = cm_s[l];
    float ps = 0.f;
    for (int n = q * 32; n < q * 32 + 32; n++) ps += __expf(S_s[n * 69 + l] - cm);
    red[tid] = ps;
  }
  __syncthreads();
  if (tid < 64)
    ics_s[tid] = 1.f / (red[tid] + red[tid + 64] + red[tid + 128] + red[tid + 192]);
  __syncthreads();
  {  // row pass, split across halves: n = tid&127, half covers 32 l's
    const int n = tid & 127, half = tid >> 7;
    const float* Sr = &S_s[n * 69];
    const int lb = half * 32, le = min(lb + 32, lv);
    float tmax = -INFINITY;
    for (int l = lb; l < le; l++) tmax = fmaxf(tmax, Sr[l]);
    red[tid] = tmax;
    __syncthreads();
    const float tm = fmaxf(red[n], red[n + 128]);
    float z = 0.f, w = 0.f;
    for (int l = lb; l < le; l++) {
      const float s = Sr[l];
      z += __expf(s - tm);
      w += __expf(s - cm_s[l]) * ics_s[l];
    }
    zb_s[tid] = z; wb_s[tid] = w;
    __syncthreads();
    if (tid < 128) {
      const size_t o = ((size_t)hb * 16 + lt) * 128 + tid;
      rmt[o] = tm;
      rzt[o] = zb_s[tid] + zb_s[tid + 128];
      rwt[o] = wb_s[tid] + wb_s[tid + 128];
    }
  }
}

// ---------------------------------------------------------------------------
// K5: combine per-tile row stats -> (m, 1/Z) and w; finalize ctx_t. grid=256.
// ---------------------------------------------------------------------------
__global__ __launch_bounds__(256) void attn_combine_kernel(
    const float* __restrict__ rmt, const float* __restrict__ rzt,
    const float* __restrict__ rwt, const float* __restrict__ dproj,
    const int* __restrict__ cnts, float* __restrict__ rm_g,
    float* __restrict__ riz_g, float* __restrict__ outp) {
  __shared__ float red[256];
  __shared__ float w_s[128];
  const int tid = threadIdx.x;
  const int hb = blockIdx.x, b = hb >> 3, h = hb & 7;
  const int ncnt = cnts[b * 2], lcnt = cnts[b * 2 + 1];
  const int ntl = (lcnt + 63) >> 6;
  if (tid < 128) {
    const int n = tid;
    float m = -INFINITY;
    for (int t = 0; t < ntl; t++)
      m = fmaxf(m, rmt[((size_t)hb * 16 + t) * 128 + n]);
    float Z = 0.f, w = 0.f;
    for (int t = 0; t < ntl; t++) {
      const size_t o = ((size_t)hb * 16 + t) * 128 + n;
      Z += rzt[o] * __expf(rmt[o] - m);
      w += rwt[o];
    }
    rm_g[hb * 128 + n] = m;
    riz_g[hb * 128 + n] = (n < ncnt) ? 1.f / Z : 0.f;
    w_s[n] = (n < ncnt) ? w : 0.f;
  }
  __syncthreads();
  const int e = tid & 63, q = tid >> 6;
  float p = 0.f;
  const int nb = q * 32, ne = min(nb + 32, ncnt);
  for (int n = nb; n < ne; n++)
    p += w_s[n] * dproj[((size_t)(b * N_ + n)) * HID_ + h * HD_ + e];
  red[tid] = p;
  __syncthreads();
  if (tid < 64) {
    const float s = red[tid] + red[tid + 64] + red[tid + 128] + red[tid + 192];
    outp[(size_t)b * (2 * HID_) + HID_ + h * HD_ + tid] = s / (float)lcnt;
  }
}

// ---------------------------------------------------------------------------
// K6: recompute S tile; v[l] = sum_n exp(S-m[n])/Z[n]; fused ctx_d partial
// accumulation (atomicAdd into zero-initialized out). grid = 256*16.
// ---------------------------------------------------------------------------
__global__ __launch_bounds__(256, 4) void attn_v_kernel(
    const unsigned short* __restrict__ thb, const unsigned short* __restrict__ dWb,
    const int* __restrict__ cnts, const float* __restrict__ rm_g,
    const float* __restrict__ riz_g, float* __restrict__ outp) {
  __shared__ float S_s[128 * 69];
  __shared__ float red[256];
  __shared__ float rm_s[128], riz_s[128], v_s[64];
  const int tid = threadIdx.x;
  const int hb = blockIdx.x >> 4, lt = blockIdx.x & 15;
  const int b = hb >> 3, h = hb & 7;
  const int ncnt = cnts[b * 2], lcnt = cnts[b * 2 + 1];
  const int l0g = lt * 64;
  if (l0g >= lcnt) return;
  const int lv = min(64, lcnt - l0g);

  if (tid < 128) {
    rm_s[tid] = rm_g[hb * 128 + tid];
    riz_s[tid] = riz_g[hb * 128 + tid];
  }
  const unsigned short* thp = thb + ((size_t)hb * L_ + l0g) * HD_;
  mfma_S_tile(thp, dWb + (size_t)hb * N_ * HD_, S_s, ncnt, lv, tid);
  __syncthreads();

  {
    const int l = tid & 63, q = tid >> 6;
    float vp = 0.f;
    for (int n = q * 32; n < q * 32 + 32; n++)
      vp += __expf(S_s[n * 69 + l] - rm_s[n]) * riz_s[n];
    red[tid] = vp;
  }
  __syncthreads();
  const float incnt = 1.f / (float)ncnt;
  if (tid < 64) {
    const float v = (tid < lv)
        ? (red[tid] + red[tid + 64] + red[tid + 128] + red[tid + 192]) * incnt
        : 0.f;
    v_s[tid] = v;
  }
  __syncthreads();
  {  // fused ctx_d partial: sum_{l in tile} v[l] * th[l][e]
    const int e = tid & 63, q = tid >> 6;
    float p = 0.f;
    for (int l = q * 16; l < q * 16 + 16; l++)
      p += v_s[l] * bf2f(thp[(size_t)l * HD_ + e]);
    red[tid] = p;
  }
  __syncthreads();
  if (tid < 64) {
    const float s = red[tid] + red[tid + 64] + red[tid + 128] + red[tid + 192];
    if (s != 0.f)
      atomicAdd(&outp[(size_t)b * (2 * HID_) + h * HD_ + tid], s);
  }
}

// ---------------------------------------------------------------------------
extern "C" void kernel_launch(void* const* d_in, const int* in_sizes, int n_in,
                              void* d_out, int out_size, void* d_ws, size_t ws_size,
                              hipStream_t stream) {
  const float* drug = (const float*)d_in[0];
  const int* dmask = (const int*)d_in[1];
  const float* tseq = (const float*)d_in[2];
  const int* tmask = (const int*)d_in[3];
  const float* Wd = (const float*)d_in[4];
  const float* bd = (const float*)d_in[5];
  const float* Wt = (const float*)d_in[6];
  const float* bt = (const float*)d_in[7];
  const float* Wb = (const float*)d_in[8];
  float* out = (float*)d_out;
  float* ws = (float*)d_ws;

  float* dp = ws + WS_D;
  float* rm = ws + WS_RM;
  float* riz = ws + WS_RIZ;
  float* rmt = ws + WS_RMT;
  float* rzt = ws + WS_RZT;
  float* rwt = ws + WS_RWT;
  int* cnts = (int*)(ws + WS_CNT);
  unsigned short* wtT = (unsigned short*)(ws + WS_WT);
  unsigned short* thb = (unsigned short*)(ws + WS_THB);
  unsigned short* dWb = (unsigned short*)(ws + WS_DWB);

  count_kernel<<<B_, 256, 0, stream>>>(dmask, tmask, cnts);
  hipMemsetAsync(out, 0, (size_t)out_size * sizeof(float), stream);
  transpose_bf16_kernel<<<dim3(HID_ / 32, TD_ / 32), 256, 0, stream>>>(Wt, wtT, TD_, HID_);
  gemm_t_mfma_kernel<<<(HID_ / 128) * ((B_ * L_) / 128), 256, 0, stream>>>(
      tseq, wtT, bt, thb, TD_);
  gemm_bias_kernel<<<dim3(HID_ / 128, (B_ * N_) / 128), 256, 0, stream>>>(
      drug, Wd, bd, dp, B_ * N_, DD_, HID_);
  dw_kernel<<<B_ * H_, 256, 0, stream>>>(dp, Wb, dWb);
  attn_stats_kernel<<<B_ * H_ * 16, 256, 0, stream>>>(thb, dWb, cnts, rwt, rmt, rzt);
  attn_combine_kernel<<<B_ * H_, 256, 0, stream>>>(rmt, rzt, rwt, dp, cnts, rm, riz, out);
  attn_v_kernel<<<B_ * H_ * 16, 256, 0, stream>>>(thb, dWb, cnts, rm, riz, out);
}

// Round 5
// 430.277 us; speedup vs baseline: 1.0923x; 1.0572x over previous
//
#include <hip/hip_runtime.h>
#include <hip/hip_bf16.h>
#include <math.h>

#define B_ 32
#define N_ 128
#define L_ 1024
#define DD_ 256
#define TD_ 1280
#define HID_ 512
#define H_ 8
#define HD_ 64

// ws layout (float offsets)
#define WS_D    0
#define WS_RM   (WS_D   + 2097152)
#define WS_RIZ  (WS_RM  + 32768)
#define WS_RMT  (WS_RIZ + 32768)
#define WS_RZT  (WS_RMT + 524288)
#define WS_RWT  (WS_RZT + 524288)
#define WS_CNT  (WS_RWT + 524288)
#define WS_WT   (WS_CNT + 64)
#define WS_THB  (WS_WT  + 327680)
#define WS_DWB  (WS_THB + 8388608)

using bf16x8 = __attribute__((ext_vector_type(8))) short;
using u16x4 = __attribute__((ext_vector_type(4))) unsigned short;
using floatx4 = __attribute__((ext_vector_type(4))) float;

static __device__ __forceinline__ unsigned short f2bf(float f) {
  unsigned int u = __float_as_uint(f);
  unsigned int r = (u + 0x7FFFu + ((u >> 16) & 1u)) >> 16;
  return (unsigned short)r;
}
static __device__ __forceinline__ float bf2f(unsigned short s) {
  return __uint_as_float(((unsigned int)s) << 16);
}
// async global->LDS DMA, 16 B per lane; LDS dest = wave-uniform base + lane*16.
static __device__ __forceinline__ void gload16(const void* g, void* l) {
  __builtin_amdgcn_global_load_lds(
      (const __attribute__((address_space(1))) void*)g,
      (__attribute__((address_space(3))) void*)l, 16, 0, 0);
}

// ---------------------------------------------------------------------------
// K0: per-batch valid counts (detect int32 vs packed-bool at runtime).
// ---------------------------------------------------------------------------
__global__ __launch_bounds__(256) void count_kernel(const int* __restrict__ dmask,
                                                    const int* __restrict__ tmask,
                                                    int* __restrict__ cnts) {
  __shared__ int red[256];
  const int b = blockIdx.x, tid = threadIdx.x;
  const bool dint = (dmask[0] == 1);
  const bool tint = (tmask[0] == 1);
  int s = 0;
  if (dint) {
    for (int i = tid; i < N_; i += 256) s += (dmask[(size_t)b*N_ + i] != 0);
  } else {
    const unsigned char* p = (const unsigned char*)dmask;
    for (int i = tid; i < N_; i += 256) s += (p[(size_t)b*N_ + i] != 0);
  }
  red[tid] = s; __syncthreads();
  for (int off = 128; off > 0; off >>= 1) { if (tid < off) red[tid] += red[tid+off]; __syncthreads(); }
  if (tid == 0) cnts[b*2] = red[0];
  __syncthreads();
  s = 0;
  if (tint) {
    for (int i = tid; i < L_; i += 256) s += (tmask[(size_t)b*L_ + i] != 0);
  } else {
    const unsigned char* p = (const unsigned char*)tmask;
    for (int i = tid; i < L_; i += 256) s += (p[(size_t)b*L_ + i] != 0);
  }
  red[tid] = s; __syncthreads();
  for (int off = 128; off > 0; off >>= 1) { if (tid < off) red[tid] += red[tid+off]; __syncthreads(); }
  if (tid == 0) cnts[b*2+1] = red[0];
}

// ---------------------------------------------------------------------------
// K0b: W (KxN fp32) -> WT (NxK bf16), 32x32 LDS tiles.
// ---------------------------------------------------------------------------
__global__ __launch_bounds__(256) void transpose_bf16_kernel(
    const float* __restrict__ W, unsigned short* __restrict__ WT, int K, int Nd) {
  __shared__ float tile[32][33];
  const int tid = threadIdx.x;
  const int n0 = blockIdx.x * 32, k0 = blockIdx.y * 32;
  const int c = tid & 31, r0 = tid >> 5;
#pragma unroll
  for (int i = 0; i < 4; i++) {
    const int r = r0 + i * 8;
    tile[c][r] = W[(size_t)(k0 + r) * Nd + n0 + c];
  }
  __syncthreads();
#pragma unroll
  for (int i = 0; i < 4; i++) {
    const int r = r0 + i * 8;
    WT[(size_t)(n0 + r) * K + k0 + c] = f2bf(tile[r][c]);
  }
}

// ---------------------------------------------------------------------------
// K1: t-projection, fused fp32->bf16. LDS-pipe analysis (round 4): at 4x4
// acc the kernel moves 0.5 ds_read_b128 + 0.25 ds_write_b64 per MFMA and the
// CU's single LDS pipe saturates (~3970 cyc/K-step/CU vs ~3600 measured wall)
// while MFMA sits at 14%. Fix: widen per-wave tile to 4x8 (BM=128, BN=256,
// 4 waves, acc[4][8]) -> per g: 4 afr (kept in regs) + 8 bfr reads for 32
// MFMAs = 0.375 reads/MFMA, A-staging writes amortized 2x. Grid 512 (2
// blocks/CU), LDS 48 KB, ~210 VGPR (2 waves/SIMD). Same coalesced A map,
// same XOR-swizzle slots, same 2-barrier schedule as round 4.
// ---------------------------------------------------------------------------
__global__ __launch_bounds__(256, 2) void gemm_t_mfma_kernel(
    const float* __restrict__ A, const unsigned short* __restrict__ WT,
    const float* __restrict__ bias, unsigned short* __restrict__ thb, int K) {
  __shared__ __align__(16) unsigned short As[8192];    // 128 rows x 64 k (2 g-sections x 512 slots)
  __shared__ __align__(16) unsigned short Bs[16384];   // 256 rows x 64 k (2 g-sections x 1024 slots)
  const int tid = threadIdx.x;
  const int lin = blockIdx.x;
  const int xcd = lin & 7, sq = lin >> 3;
  const int n_t = sq & 1, m_t = (sq >> 1) + xcd * 32;
  const int m0 = m_t * 128, n0 = n_t * 256;
  const int lane = tid & 63, wave = tid >> 6;
  const int wm = wave & 1, wn = wave >> 1;
  const int quad = lane >> 4, lrow = lane & 15;

  floatx4 acc[4][8];
#pragma unroll
  for (int i = 0; i < 4; i++)
#pragma unroll
    for (int j = 0; j < 8; j++) acc[i][j] = (floatx4){0.f, 0.f, 0.f, 0.f};

  // B staging source offsets (four calls x two kgroups; 256 rows)
  int srcoffB[4][2];
#pragma unroll
  for (int call = 0; call < 4; call++) {
    const int i = call * 256 + tid;
    const int r = i >> 2;
    const int c = (i & 3) ^ ((r >> 1) & 3);
#pragma unroll
    for (int g = 0; g < 2; g++) srcoffB[call][g] = r * K + g * 32 + c * 8;
  }

  // A staging map (coalesced): instr i covers rows i*16 + arow_ (4 rows/wave),
  // lane's 16-lane group spans one row's 64 contiguous floats.
  const int arow_ = wave * 4 + (lane >> 4);   // base row 0..15
  const int x_ = lane & 15;                    // 16-B column slot (x_*4 floats)
  const int ag_ = x_ >> 3;                     // kgroup 0/1
  const int acq_ = (x_ & 7) >> 1;              // 8-col chunk within group
  const int ahalf_ = x_ & 1;                   // half-slot (4 shorts)

  const float* Abase = A + (size_t)m0 * K;
  const unsigned short* Bbase = WT + (size_t)n0 * K;

  float4 apf[8];

  auto aload = [&](int k0) {
#pragma unroll
    for (int i = 0; i < 8; i++)
      apf[i] = *(const float4*)(Abase + (size_t)(i * 16 + arow_) * K + k0 + x_ * 4);
  };
  auto awrite = [&]() {
#pragma unroll
    for (int i = 0; i < 8; i++) {
      const int r = i * 16 + arow_;
      const int sw = (r >> 1) & 3;
      u16x4 p;
      p[0] = f2bf(apf[i].x); p[1] = f2bf(apf[i].y);
      p[2] = f2bf(apf[i].z); p[3] = f2bf(apf[i].w);
      *(u16x4*)&As[ag_ * 4096 + (r * 4 + (acq_ ^ sw)) * 8 + ahalf_ * 4] = p;
    }
  };
  auto bstage = [&](int k0) {
#pragma unroll
    for (int g = 0; g < 2; g++)
#pragma unroll
      for (int call = 0; call < 4; call++) {
        const int dst = g * 8192 + (call * 256 + wave * 64) * 8;
        gload16(Bbase + k0 + srcoffB[call][g], &Bs[dst]);
      }
  };

  const int nkt = K / 64;   // 20
  aload(0);

  for (int t = 0; t < nkt; t++) {
    __syncthreads();        // all waves done with As/Bs(t-1); drains apf loads
    bstage(t * 64);         // B DMA issue (8 gload16)
    awrite();               // As <- cvt(apf); apf older than DMA in vmcnt FIFO
    __syncthreads();        // drains B DMA; As/Bs(t) visible
    if (t + 1 < nkt) aload((t + 1) * 64);   // in flight across MFMA phase
#pragma unroll
    for (int g = 0; g < 2; g++) {
      bf16x8 afr[4];
#pragma unroll
      for (int i = 0; i < 4; i++) {
        const int ar = wm * 64 + i * 16 + lrow;
        afr[i] = *(const bf16x8*)&As[g * 4096 + (ar * 4 + (quad ^ ((ar >> 1) & 3))) * 8];
      }
#pragma unroll
      for (int jh = 0; jh < 2; jh++) {
        bf16x8 bfr[4];
#pragma unroll
        for (int j = 0; j < 4; j++) {
          const int br = wn * 128 + (jh * 4 + j) * 16 + lrow;
          bfr[j] = *(const bf16x8*)&Bs[g * 8192 + (br * 4 + (quad ^ ((br >> 1) & 3))) * 8];
        }
#pragma unroll
        for (int i = 0; i < 4; i++)
#pragma unroll
          for (int j = 0; j < 4; j++)
            acc[i][jh * 4 + j] = __builtin_amdgcn_mfma_f32_16x16x32_bf16(
                afr[i], bfr[j], acc[i][jh * 4 + j], 0, 0, 0);
      }
    }
  }

  float bj[8];
#pragma unroll
  for (int j = 0; j < 8; j++) bj[j] = bias[n0 + wn * 128 + j * 16 + lrow];
#pragma unroll
  for (int i = 0; i < 4; i++) {
#pragma unroll
    for (int j = 0; j < 8; j++) {
      const int gcol = n0 + wn * 128 + j * 16 + lrow;
      const int hh = gcol >> 6, e = gcol & 63;
#pragma unroll
      for (int r = 0; r < 4; r++) {
        const int grow = m0 + wm * 64 + i * 16 + quad * 4 + r;
        const int bb = grow >> 10, l = grow & 1023;
        thb[(((size_t)bb * H_ + hh) * L_ + l) * HD_ + e] = f2bf(acc[i][j][r] + bj[j]);
      }
    }
  }
}

// ---------------------------------------------------------------------------
// K2: fp32 GEMM for the small d-projection (keeps dproj exact for ctx_t).
// ---------------------------------------------------------------------------
__global__ __launch_bounds__(256) void gemm_bias_kernel(
    const float* __restrict__ A, const float* __restrict__ W,
    const float* __restrict__ bias, float* __restrict__ C,
    int M, int K, int Nd) {
  __shared__ float As[8][132];
  __shared__ float Bs[8][132];
  const int tid = threadIdx.x;
  const int m0 = blockIdx.y * 128, n0 = blockIdx.x * 128;
  const int lr = tid >> 1, lc = (tid & 1) * 4;
  const int wr = tid >> 5, wc = (tid & 31) * 4;
  const int tm = (tid >> 4) * 4, tn = (tid & 15) * 4;

  float acc[2][2][4][4];
#pragma unroll
  for (int a = 0; a < 2; a++)
#pragma unroll
    for (int bq = 0; bq < 2; bq++)
#pragma unroll
      for (int i = 0; i < 4; i++)
#pragma unroll
        for (int j = 0; j < 4; j++) acc[a][bq][i][j] = 0.f;

  const float* Aptr = A + (size_t)(m0 + lr) * K + lc;
  const float* Wptr = W + (size_t)wr * Nd + n0 + wc;

  for (int k0 = 0; k0 < K; k0 += 8) {
    float4 a4 = *(const float4*)(Aptr + k0);
    float4 w4 = *(const float4*)(Wptr + (size_t)k0 * Nd);
    __syncthreads();
    As[lc+0][lr] = a4.x; As[lc+1][lr] = a4.y; As[lc+2][lr] = a4.z; As[lc+3][lr] = a4.w;
    *(float4*)&Bs[wr][wc] = w4;
    __syncthreads();
#pragma unroll
    for (int kk = 0; kk < 8; kk++) {
      float4 a0 = *(const float4*)&As[kk][tm];
      float4 a1 = *(const float4*)&As[kk][tm + 64];
      float4 b0 = *(const float4*)&Bs[kk][tn];
      float4 b1 = *(const float4*)&Bs[kk][tn + 64];
      const float av0[4] = {a0.x, a0.y, a0.z, a0.w};
      const float av1[4] = {a1.x, a1.y, a1.z, a1.w};
      const float bv0[4] = {b0.x, b0.y, b0.z, b0.w};
      const float bv1[4] = {b1.x, b1.y, b1.z, b1.w};
#pragma unroll
      for (int i = 0; i < 4; i++)
#pragma unroll
        for (int j = 0; j < 4; j++) {
          acc[0][0][i][j] += av0[i] * bv0[j];
          acc[0][1][i][j] += av0[i] * bv1[j];
          acc[1][0][i][j] += av1[i] * bv0[j];
          acc[1][1][i][j] += av1[i] * bv1[j];
        }
    }
  }
  float4 bias0 = *(const float4*)&bias[n0 + tn];
  float4 bias1 = *(const float4*)&bias[n0 + tn + 64];
  const float bb0[4] = {bias0.x, bias0.y, bias0.z, bias0.w};
  const float bb1[4] = {bias1.x, bias1.y, bias1.z, bias1.w};
#pragma unroll
  for (int mh = 0; mh < 2; mh++)
#pragma unroll
    for (int i = 0; i < 4; i++) {
      const int row = m0 + mh * 64 + tm + i;
      float* cp = C + (size_t)row * Nd + n0;
      float4 o0, o1;
      o0.x = acc[mh][0][i][0] + bb0[0]; o0.y = acc[mh][0][i][1] + bb0[1];
      o0.z = acc[mh][0][i][2] + bb0[2]; o0.w = acc[mh][0][i][3] + bb0[3];
      o1.x = acc[mh][1][i][0] + bb1[0]; o1.y = acc[mh][1][i][1] + bb1[1];
      o1.z = acc[mh][1][i][2] + bb1[2]; o1.w = acc[mh][1][i][3] + bb1[3];
      *(float4*)(cp + tn) = o0;
      *(float4*)(cp + tn + 64) = o1;
    }
}

// ---------------------------------------------------------------------------
// K3: dWb[b][h][n][e] = (dh @ Wb[h]) in bf16. grid = 256 (hb = b*8+h).
// ---------------------------------------------------------------------------
__global__ __launch_bounds__(256) void dw_kernel(
    const float* __restrict__ dproj, const float* __restrict__ Wb,
    unsigned short* __restrict__ dWb) {
  __shared__ float wb_s[64 * 64];
  const int tid = threadIdx.x;
  const int hb = blockIdx.x, b = hb >> 3, h = hb & 7;
  for (int i = tid; i < 4096; i += 256) wb_s[i] = Wb[(size_t)h * 4096 + i];
  __syncthreads();
  const int n = tid >> 1, half = tid & 1;
  float acc[32];
#pragma unroll
  for (int e = 0; e < 32; e++) acc[e] = 0.f;
  const float* dpr = dproj + ((size_t)(b * N_ + n)) * HID_ + h * HD_;
  for (int k = 0; k < 64; k++) {
    const float a = dpr[k];
    const float* wr = &wb_s[k * 64 + half * 32];
#pragma unroll
    for (int e = 0; e < 32; e++) acc[e] += a * wr[e];
  }
  unsigned short* outp = dWb + ((size_t)hb * N_ + n) * HD_ + half * 32;
#pragma unroll
  for (int e = 0; e < 32; e++) outp[e] = f2bf(acc[e]);
}

// ---------------------------------------------------------------------------
// S-tile (128n x 64l) via MFMA, operands from global bf16 head-major arrays;
// masked fp32 S to LDS (stride 69: conflict-light on row and column walks).
// ---------------------------------------------------------------------------
__device__ __forceinline__ void mfma_S_tile(
    const unsigned short* __restrict__ thp, const unsigned short* __restrict__ dwp,
    float* __restrict__ S_s, int ncnt, int lv, int tid) {
  const int lane = tid & 63, wave = tid >> 6;
  const int quad = lane >> 4, lr = lane & 15;
  const int noff = (wave & 1) * 64, loff = (wave >> 1) * 32;

  floatx4 acc[4][2];
#pragma unroll
  for (int i = 0; i < 4; i++)
#pragma unroll
    for (int j = 0; j < 2; j++) acc[i][j] = (floatx4){0.f, 0.f, 0.f, 0.f};

#pragma unroll
  for (int kc = 0; kc < 2; kc++) {
    bf16x8 bfr[2];
#pragma unroll
    for (int j = 0; j < 2; j++)
      bfr[j] = *(const bf16x8*)&thp[(size_t)(loff + j * 16 + lr) * HD_ + kc * 32 + quad * 8];
#pragma unroll
    for (int i = 0; i < 4; i++) {
      bf16x8 afr = *(const bf16x8*)&dwp[(size_t)(noff + i * 16 + lr) * HD_ + kc * 32 + quad * 8];
#pragma unroll
      for (int j = 0; j < 2; j++)
        acc[i][j] = __builtin_amdgcn_mfma_f32_16x16x32_bf16(afr, bfr[j], acc[i][j], 0, 0, 0);
    }
  }
#pragma unroll
  for (int i = 0; i < 4; i++)
#pragma unroll
    for (int j = 0; j < 2; j++)
#pragma unroll
      for (int r = 0; r < 4; r++) {
        const int n = noff + i * 16 + quad * 4 + r;
        const int li = loff + j * 16 + lr;
        const bool ok = (n < ncnt) && (li < lv);
        S_s[n * 69 + li] = ok ? acc[i][j][r] : -1e9f;
      }
}

// ---------------------------------------------------------------------------
// K4: per (hb, lt): S tile -> column softmax (complete per tile); per-tile
// row stats (m_t, z_t) and per-tile w partial (no atomics). grid = 256*16.
// ---------------------------------------------------------------------------
__global__ __launch_bounds__(256, 4) void attn_stats_kernel(
    const unsigned short* __restrict__ thb, const unsigned short* __restrict__ dWb,
    const int* __restrict__ cnts, float* __restrict__ rwt,
    float* __restrict__ rmt, float* __restrict__ rzt) {
  __shared__ float S_s[128 * 69];
  __shared__ float red[256];
  __shared__ float zb_s[256], wb_s[256];
  __shared__ float cm_s[64], ics_s[64];
  const int tid = threadIdx.x;
  const int hb = blockIdx.x >> 4, lt = blockIdx.x & 15;
  const int b = hb >> 3;
  const int ncnt = cnts[b * 2], lcnt = cnts[b * 2 + 1];
  const int l0g = lt * 64;
  if (l0g >= lcnt) return;
  const int lv = min(64, lcnt - l0g);

  mfma_S_tile(thb + ((size_t)hb * L_ + l0g) * HD_, dWb + (size_t)hb * N_ * HD_,
              S_s, ncnt, lv, tid);
  __syncthreads();

  {  // column max partials (over n)
    const int l = tid & 63, q = tid >> 6;
    float pm = -INFINITY;
    for (int n = q * 32; n < q * 32 + 32; n++) pm = fmaxf(pm, S_s[n * 69 + l]);
    red[tid] = pm;
  }
  __syncthreads();
  if (tid < 64)
    cm_s[tid] = fmaxf(fmaxf(red[tid], red[tid + 64]), fmaxf(red[tid + 128], red[tid + 192]));
  __syncthreads();
  {  // column expsum partials
    const int l = tid & 63, q = tid >> 6;
    const float cm = cm_s[l];
    float ps = 0.f;
    for (int n = q * 32; n < q * 32 + 32; n++) ps += __expf(S_s[n * 69 + l] - cm);
    red[tid] = ps;
  }
  __syncthreads();
  if (tid < 64)
    ics_s[tid] = 1.f / (red[tid] + red[tid + 64] + red[tid + 128] + red[tid + 192]);
  __syncthreads();
  {  // row pass, split across halves: n = tid&127, half covers 32 l's
    const int n = tid & 127, half = tid >> 7;
    const float* Sr = &S_s[n * 69];
    const int lb = half * 32, le = min(lb + 32, lv);
    float tmax = -INFINITY;
    for (int l = lb; l < le; l++) tmax = fmaxf(tmax, Sr[l]);
    red[tid] = tmax;
    __syncthreads();
    const float tm = fmaxf(red[n], red[n + 128]);
    float z = 0.f, w = 0.f;
    for (int l = lb; l < le; l++) {
      const float s = Sr[l];
      z += __expf(s - tm);
      w += __expf(s - cm_s[l]) * ics_s[l];
    }
    zb_s[tid] = z; wb_s[tid] = w;
    __syncthreads();
    if (tid < 128) {
      const size_t o = ((size_t)hb * 16 + lt) * 128 + tid;
      rmt[o] = tm;
      rzt[o] = zb_s[tid] + zb_s[tid + 128];
      rwt[o] = wb_s[tid] + wb_s[tid + 128];
    }
  }
}

// ---------------------------------------------------------------------------
// K5: combine per-tile row stats -> (m, 1/Z) and w; finalize ctx_t. grid=256.
// ---------------------------------------------------------------------------
__global__ __launch_bounds__(256) void attn_combine_kernel(
    const float* __restrict__ rmt, const float* __restrict__ rzt,
    const float* __restrict__ rwt, const float* __restrict__ dproj,
    const int* __restrict__ cnts, float* __restrict__ rm_g,
    float* __restrict__ riz_g, float* __restrict__ outp) {
  __shared__ float red[256];
  __shared__ float w_s[128];
  const int tid = threadIdx.x;
  const int hb = blockIdx.x, b = hb >> 3, h = hb & 7;
  const int ncnt = cnts[b * 2], lcnt = cnts[b * 2 + 1];
  const int ntl = (lcnt + 63) >> 6;
  if (tid < 128) {
    const int n = tid;
    float m = -INFINITY;
    for (int t = 0; t < ntl; t++)
      m = fmaxf(m, rmt[((size_t)hb * 16 + t) * 128 + n]);
    float Z = 0.f, w = 0.f;
    for (int t = 0; t < ntl; t++) {
      const size_t o = ((size_t)hb * 16 + t) * 128 + n;
      Z += rzt[o] * __expf(rmt[o] - m);
      w += rwt[o];
    }
    rm_g[hb * 128 + n] = m;
    riz_g[hb * 128 + n] = (n < ncnt) ? 1.f / Z : 0.f;
    w_s[n] = (n < ncnt) ? w : 0.f;
  }
  __syncthreads();
  const int e = tid & 63, q = tid >> 6;
  float p = 0.f;
  const int nb = q * 32, ne = min(nb + 32, ncnt);
  for (int n = nb; n < ne; n++)
    p += w_s[n] * dproj[((size_t)(b * N_ + n)) * HID_ + h * HD_ + e];
  red[tid] = p;
  __syncthreads();
  if (tid < 64) {
    const float s = red[tid] + red[tid + 64] + red[tid + 128] + red[tid + 192];
    outp[(size_t)b * (2 * HID_) + HID_ + h * HD_ + tid] = s / (float)lcnt;
  }
}

// ---------------------------------------------------------------------------
// K6: recompute S tile; v[l] = sum_n exp(S-m[n])/Z[n]; fused ctx_d partial
// accumulation (atomicAdd into zero-initialized out). grid = 256*16.
// ---------------------------------------------------------------------------
__global__ __launch_bounds__(256, 4) void attn_v_kernel(
    const unsigned short* __restrict__ thb, const unsigned short* __restrict__ dWb,
    const int* __restrict__ cnts, const float* __restrict__ rm_g,
    const float* __restrict__ riz_g, float* __restrict__ outp) {
  __shared__ float S_s[128 * 69];
  __shared__ float red[256];
  __shared__ float rm_s[128], riz_s[128], v_s[64];
  const int tid = threadIdx.x;
  const int hb = blockIdx.x >> 4, lt = blockIdx.x & 15;
  const int b = hb >> 3, h = hb & 7;
  const int ncnt = cnts[b * 2], lcnt = cnts[b * 2 + 1];
  const int l0g = lt * 64;
  if (l0g >= lcnt) return;
  const int lv = min(64, lcnt - l0g);

  if (tid < 128) {
    rm_s[tid] = rm_g[hb * 128 + tid];
    riz_s[tid] = riz_g[hb * 128 + tid];
  }
  const unsigned short* thp = thb + ((size_t)hb * L_ + l0g) * HD_;
  mfma_S_tile(thp, dWb + (size_t)hb * N_ * HD_, S_s, ncnt, lv, tid);
  __syncthreads();

  {
    const int l = tid & 63, q = tid >> 6;
    float vp = 0.f;
    for (int n = q * 32; n < q * 32 + 32; n++)
      vp += __expf(S_s[n * 69 + l] - rm_s[n]) * riz_s[n];
    red[tid] = vp;
  }
  __syncthreads();
  const float incnt = 1.f / (float)ncnt;
  if (tid < 64) {
    const float v = (tid < lv)
        ? (red[tid] + red[tid + 64] + red[tid + 128] + red[tid + 192]) * incnt
        : 0.f;
    v_s[tid] = v;
  }
  __syncthreads();
  {  // fused ctx_d partial: sum_{l in tile} v[l] * th[l][e]
    const int e = tid & 63, q = tid >> 6;
    float p = 0.f;
    for (int l = q * 16; l < q * 16 + 16; l++)
      p += v_s[l] * bf2f(thp[(size_t)l * HD_ + e]);
    red[tid] = p;
  }
  __syncthreads();
  if (tid < 64) {
    const float s = red[tid] + red[tid + 64] + red[tid + 128] + red[tid + 192];
    if (s != 0.f)
      atomicAdd(&outp[(size_t)b * (2 * HID_) + h * HD_ + tid], s);
  }
}

// ---------------------------------------------------------------------------
extern "C" void kernel_launch(void* const* d_in, const int* in_sizes, int n_in,
                              void* d_out, int out_size, void* d_ws, size_t ws_size,
                              hipStream_t stream) {
  const float* drug = (const float*)d_in[0];
  const int* dmask = (const int*)d_in[1];
  const float* tseq = (const float*)d_in[2];
  const int* tmask = (const int*)d_in[3];
  const float* Wd = (const float*)d_in[4];
  const float* bd = (const float*)d_in[5];
  const float* Wt = (const float*)d_in[6];
  const float* bt = (const float*)d_in[7];
  const float* Wb = (const float*)d_in[8];
  float* out = (float*)d_out;
  float* ws = (float*)d_ws;

  float* dp = ws + WS_D;
  float* rm = ws + WS_RM;
  float* riz = ws + WS_RIZ;
  float* rmt = ws + WS_RMT;
  float* rzt = ws + WS_RZT;
  float* rwt = ws + WS_RWT;
  int* cnts = (int*)(ws + WS_CNT);
  unsigned short* wtT = (unsigned short*)(ws + WS_WT);
  unsigned short* thb = (unsigned short*)(ws + WS_THB);
  unsigned short* dWb = (unsigned short*)(ws + WS_DWB);

  count_kernel<<<B_, 256, 0, stream>>>(dmask, tmask, cnts);
  hipMemsetAsync(out, 0, (size_t)out_size * sizeof(float), stream);
  transpose_bf16_kernel<<<dim3(HID_ / 32, TD_ / 32), 256, 0, stream>>>(Wt, wtT, TD_, HID_);
  gemm_t_mfma_kernel<<<(HID_ / 256) * ((B_ * L_) / 128), 256, 0, stream>>>(
      tseq, wtT, bt, thb, TD_);
  gemm_bias_kernel<<<dim3(HID_ / 128, (B_ * N_) / 128), 256, 0, stream>>>(
      drug, Wd, bd, dp, B_ * N_, DD_, HID_);
  dw_kernel<<<B_ * H_, 256, 0, stream>>>(dp, Wb, dWb);
  attn_stats_kernel<<<B_ * H_ * 16, 256, 0, stream>>>(thb, dWb, cnts, rwt, rmt, rzt);
  attn_combine_kernel<<<B_ * H_, 256, 0, stream>>>(rmt, rzt, rwt, dp, cnts, rm, riz, out);
  attn_v_kernel<<<B_ * H_ * 16, 256, 0, stream>>>(thb, dWb, cnts, rm, riz, out);
}